// Round 1
// baseline (180.359 us; speedup 1.0000x reference)
//
#include <hip/hip_runtime.h>

#define BB 4
#define CC 64
#define HH 192
#define WW 192
#define HWN (HH*WW)            // 36864
#define KH 4
#define KW 16
#define PW (WW/KW)             // 12
#define MP ((HH/KH)*(WW/KW))   // 576
#define NT 128                 // n-tile per block
#define MT 64                  // m-tile per iteration
#define MITER (MP/MT)          // 9
#define SCALE_W 65536.0f
#define INV_SCALE (1.0f/65536.0f)

typedef _Float16 half8 __attribute__((ext_vector_type(8)));
typedef float floatx4 __attribute__((ext_vector_type(4)));

// ---------------- pooling: Kp^T (f16, [b][m][c]) and Vp (f32, [b][c][m]) ----
__global__ __launch_bounds__(256) void pool_kernel(
    const float* __restrict__ Kin, const float* __restrict__ Vin,
    _Float16* __restrict__ kpt, float* __restrict__ vp) {
  int t = blockIdx.x * 256 + threadIdx.x;
  const int total = BB * CC * MP;
  bool isV = t >= total;
  int idx = isV ? t - total : t;
  int m = idx % MP;
  int c = (idx / MP) % CC;
  int b = idx / (MP * CC);
  int mh = m / PW, mw = m % PW;
  const float* src = (isV ? Vin : Kin) + (((b * CC + c) * HH + mh * KH) * WW + mw * KW);
  float s = 0.f;
#pragma unroll
  for (int r = 0; r < KH; ++r) {
    const float4* row = (const float4*)(src + r * WW);
#pragma unroll
    for (int j = 0; j < KW / 4; ++j) {
      float4 v = row[j];
      s += v.x + v.y + v.z + v.w;
    }
  }
  s *= (1.0f / (KH * KW));
  if (isV) vp[(b * CC + c) * MP + m] = s;
  else     kpt[(b * MP + m) * CC + c] = (_Float16)s;
}

// ---------------- pass A: colsum[b][m] = sum_n exp(scores[b][n][m]) --------
__global__ __launch_bounds__(256) void colsum_kernel(
    const float* __restrict__ Q, const _Float16* __restrict__ kpt,
    float* __restrict__ colsum) {
  __shared__ float cs[MP];
  int b = blockIdx.y;
  int n0 = blockIdx.x * NT;
  int tid = threadIdx.x;
  int wv = tid >> 6;
  int lane = tid & 63;
  int l15 = lane & 15, lhi = lane >> 4;

  for (int i = tid; i < MP; i += 256) cs[i] = 0.f;
  __syncthreads();

  // A-fragments: rows = n (16/frag), k = c. Q is [c][n] -> 64B-coalesced per e.
  const float* Qb = Q + b * CC * HWN;
  int nrow = n0 + wv * 32 + l15;
  half8 afrag[2][2];
#pragma unroll
  for (int nf = 0; nf < 2; ++nf)
#pragma unroll
    for (int ks = 0; ks < 2; ++ks) {
      int cbase = ks * 32 + lhi * 8;
      int n = nrow + nf * 16;
#pragma unroll
      for (int e = 0; e < 8; ++e)
        afrag[nf][ks][e] = (_Float16)Qb[(cbase + e) * HWN + n];
    }

  const _Float16* kb = kpt + b * MP * CC;
  for (int mi = 0; mi < MITER; ++mi) {
    half8 bfrag[4][2];
#pragma unroll
    for (int mf = 0; mf < 4; ++mf)
#pragma unroll
      for (int ks = 0; ks < 2; ++ks) {
        int m = mi * MT + mf * 16 + l15;
        bfrag[mf][ks] = *(const half8*)(kb + m * CC + ks * 32 + lhi * 8);
      }
    floatx4 zero = {0.f, 0.f, 0.f, 0.f};
    floatx4 sacc[2][4];
#pragma unroll
    for (int nf = 0; nf < 2; ++nf)
#pragma unroll
      for (int mf = 0; mf < 4; ++mf) sacc[nf][mf] = zero;
#pragma unroll
    for (int ks = 0; ks < 2; ++ks)
#pragma unroll
      for (int nf = 0; nf < 2; ++nf)
#pragma unroll
        for (int mf = 0; mf < 4; ++mf)
          sacc[nf][mf] = __builtin_amdgcn_mfma_f32_16x16x32_f16(
              afrag[nf][ks], bfrag[mf][ks], sacc[nf][mf], 0, 0, 0);
    // exp + column (n) reduce: rows live in regs + lane>>4 groups
#pragma unroll
    for (int mf = 0; mf < 4; ++mf) {
      float s = 0.f;
#pragma unroll
      for (int nf = 0; nf < 2; ++nf)
#pragma unroll
        for (int r = 0; r < 4; ++r)
          s += __expf(sacc[nf][mf][r]);
      s += __shfl_xor(s, 16);
      s += __shfl_xor(s, 32);
      if (lane < 16) atomicAdd(&cs[mi * MT + mf * 16 + l15], s);
    }
  }
  __syncthreads();
  for (int i = tid; i < MP; i += 256) atomicAdd(&colsum[b * MP + i], cs[i]);
}

// ---------------- W' = Vp/colsum * 2^16 (f16, [b][c][m]) -------------------
__global__ __launch_bounds__(256) void wprep_kernel(
    const float* __restrict__ vp, const float* __restrict__ colsum,
    _Float16* __restrict__ wq) {
  int t = blockIdx.x * 256 + threadIdx.x;
  int m = t % MP;
  int b = t / (CC * MP);
  wq[t] = (_Float16)(vp[t] / colsum[b * MP + m] * SCALE_W);
}

// ---------------- pass B: out[b][c][n] = sum_m W'[c][m]*E[n][m] * 2^-16 ----
__global__ __launch_bounds__(256) void attn_main_kernel(
    const float* __restrict__ Q, const _Float16* __restrict__ kpt,
    const _Float16* __restrict__ wq, float* __restrict__ out) {
  // per-wave private E tile: 32 n rows x 64 m (f16), 16B-slot XOR swizzle
  __shared__ float4 elds4[1024];  // 16 KB
  char* elds = (char*)elds4;
  int b = blockIdx.y;
  int n0 = blockIdx.x * NT;
  int tid = threadIdx.x;
  int wv = tid >> 6;
  int lane = tid & 63;
  int l15 = lane & 15, lhi = lane >> 4;
  char* ebase = elds + wv * 4096;

  const float* Qb = Q + b * CC * HWN;
  int nrow = n0 + wv * 32 + l15;
  half8 afrag[2][2];
#pragma unroll
  for (int nf = 0; nf < 2; ++nf)
#pragma unroll
    for (int ks = 0; ks < 2; ++ks) {
      int cbase = ks * 32 + lhi * 8;
      int n = nrow + nf * 16;
#pragma unroll
      for (int e = 0; e < 8; ++e)
        afrag[nf][ks][e] = (_Float16)Qb[(cbase + e) * HWN + n];
    }

  floatx4 zero = {0.f, 0.f, 0.f, 0.f};
  floatx4 oacc[4][2];
#pragma unroll
  for (int cf = 0; cf < 4; ++cf)
#pragma unroll
    for (int nf = 0; nf < 2; ++nf) oacc[cf][nf] = zero;

  const _Float16* kb = kpt + b * MP * CC;
  const _Float16* wb = wq + b * CC * MP;

  for (int mi = 0; mi < MITER; ++mi) {
    // ---- GEMM1: scores tile [32n x 64m] ----
    half8 bfrag[4][2];
#pragma unroll
    for (int mf = 0; mf < 4; ++mf)
#pragma unroll
      for (int ks = 0; ks < 2; ++ks) {
        int m = mi * MT + mf * 16 + l15;
        bfrag[mf][ks] = *(const half8*)(kb + m * CC + ks * 32 + lhi * 8);
      }
    floatx4 sacc[2][4];
#pragma unroll
    for (int nf = 0; nf < 2; ++nf)
#pragma unroll
      for (int mf = 0; mf < 4; ++mf) sacc[nf][mf] = zero;
#pragma unroll
    for (int ks = 0; ks < 2; ++ks)
#pragma unroll
      for (int nf = 0; nf < 2; ++nf)
#pragma unroll
        for (int mf = 0; mf < 4; ++mf)
          sacc[nf][mf] = __builtin_amdgcn_mfma_f32_16x16x32_f16(
              afrag[nf][ks], bfrag[mf][ks], sacc[nf][mf], 0, 0, 0);

    // ---- exp -> f16 -> swizzled per-wave LDS (no cross-wave deps) ----
#pragma unroll
    for (int nf = 0; nf < 2; ++nf)
#pragma unroll
      for (int mf = 0; mf < 4; ++mf)
#pragma unroll
        for (int r = 0; r < 4; ++r) {
          int nl = nf * 16 + lhi * 4 + r;   // 0..31 (wave-local n)
          int ml = mf * 16 + l15;           // 0..63
          float ev = __expf(sacc[nf][mf][r]);
          int byte = nl * 128 + ((((ml >> 3) ^ (nl & 7))) << 4) + ((ml & 7) << 1);
          *(_Float16*)(ebase + byte) = (_Float16)ev;
        }

    // ---- GEMM2: oacc[c][n] += W'[c][m-tile] * E^T[m-tile][n] ----
    half8 wfrag[4][2];
#pragma unroll
    for (int cf = 0; cf < 4; ++cf)
#pragma unroll
      for (int ks = 0; ks < 2; ++ks)
        wfrag[cf][ks] = *(const half8*)(wb + (cf * 16 + l15) * MP + mi * MT + ks * 32 + lhi * 8);
    half8 efrag[2][2];
#pragma unroll
    for (int nf = 0; nf < 2; ++nf)
#pragma unroll
      for (int ks = 0; ks < 2; ++ks) {
        int nl = nf * 16 + l15;
        int slot = (ks * 4 + lhi) ^ (nl & 7);
        efrag[nf][ks] = *(const half8*)(ebase + nl * 128 + (slot << 4));
      }
#pragma unroll
    for (int ks = 0; ks < 2; ++ks)
#pragma unroll
      for (int cf = 0; cf < 4; ++cf)
#pragma unroll
        for (int nf = 0; nf < 2; ++nf)
          oacc[cf][nf] = __builtin_amdgcn_mfma_f32_16x16x32_f16(
              wfrag[cf][ks], efrag[nf][ks], oacc[cf][nf], 0, 0, 0);
  }

  // ---- store: D rows = c, cols = n -> 64B-coalesced per 16-lane group ----
  float* ob = out + b * CC * HWN;
#pragma unroll
  for (int cf = 0; cf < 4; ++cf)
#pragma unroll
    for (int nf = 0; nf < 2; ++nf)
#pragma unroll
      for (int r = 0; r < 4; ++r) {
        int c = cf * 16 + lhi * 4 + r;
        int n = n0 + wv * 32 + nf * 16 + l15;
        ob[c * HWN + n] = oacc[cf][nf][r] * INV_SCALE;
      }
}

extern "C" void kernel_launch(void* const* d_in, const int* in_sizes, int n_in,
                              void* d_out, int out_size, void* d_ws, size_t ws_size,
                              hipStream_t stream) {
  const float* K = (const float*)d_in[0];
  const float* Q = (const float*)d_in[1];
  const float* V = (const float*)d_in[2];
  float* out = (float*)d_out;
  char* ws = (char*)d_ws;
  // ws layout (all 256B-aligned): kpt f16 | vp f32 | wq f16 | colsum f32
  _Float16* kpt   = (_Float16*)(ws);                          // 294912 B
  float*    vp    = (float*)(ws + 294912);                    // 589824 B
  _Float16* wq    = (_Float16*)(ws + 294912 + 589824);        // 294912 B
  float*    colsum = (float*)(ws + 294912 + 589824 + 294912); // 9216 B

  hipMemsetAsync(colsum, 0, BB * MP * sizeof(float), stream);
  pool_kernel<<<(2 * BB * CC * MP) / 256, 256, 0, stream>>>(K, V, kpt, vp);
  colsum_kernel<<<dim3(HWN / NT, BB), 256, 0, stream>>>(Q, kpt, colsum);
  wprep_kernel<<<(BB * CC * MP) / 256, 256, 0, stream>>>(vp, colsum, wq);
  attn_main_kernel<<<dim3(HWN / NT, BB), 256, 0, stream>>>(Q, kpt, wq, out);
}

// Round 2
// 160.784 us; speedup vs baseline: 1.1217x; 1.1217x over previous
//
#include <hip/hip_runtime.h>

#define BB 4
#define CC 64
#define HH 192
#define WW 192
#define HWN (HH*WW)            // 36864
#define KH 4
#define KW 16
#define PW (WW/KW)             // 12
#define MP ((HH/KH)*(WW/KW))   // 576
#define NT 128                 // n-tile per block
#define MT 64                  // m-tile per iteration
#define MITER (MP/MT)          // 9
#define SCALE_W 65536.0f
#define INV_SCALE (1.0f/65536.0f)

typedef _Float16 half8 __attribute__((ext_vector_type(8)));
typedef _Float16 half4 __attribute__((ext_vector_type(4)));
typedef float floatx4 __attribute__((ext_vector_type(4)));

// ---------------- pooling: Kp^T (f16, [b][m][c]) and Vp (f32, [b][c][m]) ----
__global__ __launch_bounds__(256) void pool_kernel(
    const float* __restrict__ Kin, const float* __restrict__ Vin,
    _Float16* __restrict__ kpt, float* __restrict__ vp) {
  int t = blockIdx.x * 256 + threadIdx.x;
  const int total = BB * CC * MP;
  bool isV = t >= total;
  int idx = isV ? t - total : t;
  int m = idx % MP;
  int c = (idx / MP) % CC;
  int b = idx / (MP * CC);
  int mh = m / PW, mw = m % PW;
  const float* src = (isV ? Vin : Kin) + (((b * CC + c) * HH + mh * KH) * WW + mw * KW);
  float s = 0.f;
#pragma unroll
  for (int r = 0; r < KH; ++r) {
    const float4* row = (const float4*)(src + r * WW);
#pragma unroll
    for (int j = 0; j < KW / 4; ++j) {
      float4 v = row[j];
      s += v.x + v.y + v.z + v.w;
    }
  }
  s *= (1.0f / (KH * KW));
  if (isV) vp[(b * CC + c) * MP + m] = s;
  else     kpt[(b * MP + m) * CC + c] = (_Float16)s;
}

// ---------------- pass A: colsum[b][m] = sum_n exp(scores[b][n][m]) --------
__global__ __launch_bounds__(256) void colsum_kernel(
    const float* __restrict__ Q, const _Float16* __restrict__ kpt,
    float* __restrict__ colsum) {
  __shared__ float cs[MP];
  int b = blockIdx.y;
  int n0 = blockIdx.x * NT;
  int tid = threadIdx.x;
  int wv = tid >> 6;
  int lane = tid & 63;
  int l15 = lane & 15, lhi = lane >> 4;

  for (int i = tid; i < MP; i += 256) cs[i] = 0.f;
  __syncthreads();

  // A-fragments: rows = n (16/frag), k = c. Q is [c][n] -> 64B-coalesced per e.
  const float* Qb = Q + b * CC * HWN;
  int nrow = n0 + wv * 32 + l15;
  half8 afrag[2][2];
#pragma unroll
  for (int nf = 0; nf < 2; ++nf)
#pragma unroll
    for (int ks = 0; ks < 2; ++ks) {
      int cbase = ks * 32 + lhi * 8;
      int n = nrow + nf * 16;
#pragma unroll
      for (int e = 0; e < 8; ++e)
        afrag[nf][ks][e] = (_Float16)Qb[(cbase + e) * HWN + n];
    }

  const _Float16* kb = kpt + b * MP * CC;
  floatx4 zero = {0.f, 0.f, 0.f, 0.f};

  // software-pipelined m-loop: bfrag(mi+1) prefetched during exp/reduce of mi
  half8 bfrag[4][2];
#pragma unroll
  for (int mf = 0; mf < 4; ++mf)
#pragma unroll
    for (int ks = 0; ks < 2; ++ks)
      bfrag[mf][ks] = *(const half8*)(kb + (mf * 16 + l15) * CC + ks * 32 + lhi * 8);

#pragma unroll
  for (int mi = 0; mi < MITER; ++mi) {
    // prefetch next tile first (younger than nothing; flies under MFMA+exp)
    half8 bnext[4][2];
    if (mi + 1 < MITER) {
#pragma unroll
      for (int mf = 0; mf < 4; ++mf)
#pragma unroll
        for (int ks = 0; ks < 2; ++ks)
          bnext[mf][ks] = *(const half8*)(kb + ((mi + 1) * MT + mf * 16 + l15) * CC + ks * 32 + lhi * 8);
    }
    floatx4 sacc[2][4];
#pragma unroll
    for (int nf = 0; nf < 2; ++nf)
#pragma unroll
      for (int mf = 0; mf < 4; ++mf) sacc[nf][mf] = zero;
#pragma unroll
    for (int ks = 0; ks < 2; ++ks)
#pragma unroll
      for (int nf = 0; nf < 2; ++nf)
#pragma unroll
        for (int mf = 0; mf < 4; ++mf)
          sacc[nf][mf] = __builtin_amdgcn_mfma_f32_16x16x32_f16(
              afrag[nf][ks], bfrag[mf][ks], sacc[nf][mf], 0, 0, 0);
    // exp + column (n) reduce: rows live in regs + lane>>4 groups
#pragma unroll
    for (int mf = 0; mf < 4; ++mf) {
      float s = 0.f;
#pragma unroll
      for (int nf = 0; nf < 2; ++nf)
#pragma unroll
        for (int r = 0; r < 4; ++r)
          s += __expf(sacc[nf][mf][r]);
      s += __shfl_xor(s, 16);
      s += __shfl_xor(s, 32);
      if (lane < 16) atomicAdd(&cs[mi * MT + mf * 16 + l15], s);
    }
    if (mi + 1 < MITER) {
#pragma unroll
      for (int mf = 0; mf < 4; ++mf)
#pragma unroll
        for (int ks = 0; ks < 2; ++ks)
          bfrag[mf][ks] = bnext[mf][ks];
    }
  }
  __syncthreads();
  for (int i = tid; i < MP; i += 256) atomicAdd(&colsum[b * MP + i], cs[i]);
}

// ---------------- W' = Vp/colsum * 2^16 (f16, [b][c][m]) -------------------
__global__ __launch_bounds__(256) void wprep_kernel(
    const float* __restrict__ vp, const float* __restrict__ colsum,
    _Float16* __restrict__ wq) {
  int t = blockIdx.x * 256 + threadIdx.x;
  int m = t % MP;
  int b = t / (CC * MP);
  wq[t] = (_Float16)(vp[t] / colsum[b * MP + m] * SCALE_W);
}

// ---------------- pass B: out[b][c][n] = sum_m W'[c][m]*E[n][m] * 2^-16 ----
// GEMM1 B-columns permuted: output col j of tile mf holds m = mi*64 + 4*j + mf,
// so each lane's 4 mf-values are consecutive m -> pack half4 -> 8 ds_write_b64.
__global__ __launch_bounds__(256) void attn_main_kernel(
    const float* __restrict__ Q, const _Float16* __restrict__ kpt,
    const _Float16* __restrict__ wq, float* __restrict__ out) {
  // per-wave private E tile: 32 n rows x 64 m (f16), 16B-slot XOR swizzle
  __shared__ float4 elds4[1024];  // 16 KB
  char* elds = (char*)elds4;
  int b = blockIdx.y;
  int n0 = blockIdx.x * NT;
  int tid = threadIdx.x;
  int wv = tid >> 6;
  int lane = tid & 63;
  int l15 = lane & 15, lhi = lane >> 4;
  char* ebase = elds + wv * 4096;

  const float* Qb = Q + b * CC * HWN;
  int nrow = n0 + wv * 32 + l15;
  half8 afrag[2][2];
#pragma unroll
  for (int nf = 0; nf < 2; ++nf)
#pragma unroll
    for (int ks = 0; ks < 2; ++ks) {
      int cbase = ks * 32 + lhi * 8;
      int n = nrow + nf * 16;
#pragma unroll
      for (int e = 0; e < 8; ++e)
        afrag[nf][ks][e] = (_Float16)Qb[(cbase + e) * HWN + n];
    }

  floatx4 zero = {0.f, 0.f, 0.f, 0.f};
  floatx4 oacc[4][2];
#pragma unroll
  for (int cf = 0; cf < 4; ++cf)
#pragma unroll
    for (int nf = 0; nf < 2; ++nf) oacc[cf][nf] = zero;

  const _Float16* kb = kpt + b * MP * CC;
  const _Float16* wb = wq + b * CC * MP;

  // prologue: bfrag(0), permuted rows m = 4*l15 + mf
  half8 bfrag[4][2];
#pragma unroll
  for (int mf = 0; mf < 4; ++mf)
#pragma unroll
    for (int ks = 0; ks < 2; ++ks)
      bfrag[mf][ks] = *(const half8*)(kb + (l15 * 4 + mf) * CC + ks * 32 + lhi * 8);

#pragma unroll
  for (int mi = 0; mi < MITER; ++mi) {
    // ---- issue wfrag loads first (consumed at GEMM2, ~600cy later) ----
    half8 wfrag[4][2];
#pragma unroll
    for (int cf = 0; cf < 4; ++cf)
#pragma unroll
      for (int ks = 0; ks < 2; ++ks)
        wfrag[cf][ks] = *(const half8*)(wb + (cf * 16 + l15) * MP + mi * MT + ks * 32 + lhi * 8);

    // ---- prefetch next bfrag (younger than wfrag: counted vmcnt keeps it in flight) ----
    half8 bnext[4][2];
    if (mi + 1 < MITER) {
#pragma unroll
      for (int mf = 0; mf < 4; ++mf)
#pragma unroll
        for (int ks = 0; ks < 2; ++ks)
          bnext[mf][ks] = *(const half8*)(kb + ((mi + 1) * MT + l15 * 4 + mf) * CC + ks * 32 + lhi * 8);
    }

    // ---- GEMM1: scores tile [32n x 64m], cols permuted ----
    floatx4 sacc[2][4];
#pragma unroll
    for (int nf = 0; nf < 2; ++nf)
#pragma unroll
      for (int mf = 0; mf < 4; ++mf) sacc[nf][mf] = zero;
#pragma unroll
    for (int ks = 0; ks < 2; ++ks)
#pragma unroll
      for (int nf = 0; nf < 2; ++nf)
#pragma unroll
        for (int mf = 0; mf < 4; ++mf)
          sacc[nf][mf] = __builtin_amdgcn_mfma_f32_16x16x32_f16(
              afrag[nf][ks], bfrag[mf][ks], sacc[nf][mf], 0, 0, 0);

    // ---- exp -> f16 -> packed swizzled per-wave LDS (8x ds_write_b64) ----
    // lane (l15,lhi): value of sacc[nf][mf][r] is E[n = nf*16+lhi*4+r][m = l15*4+mf]
#pragma unroll
    for (int nf = 0; nf < 2; ++nf)
#pragma unroll
      for (int r = 0; r < 4; ++r) {
        int nl = nf * 16 + lhi * 4 + r;   // 0..31 (wave-local n)
        half4 h;
#pragma unroll
        for (int mf = 0; mf < 4; ++mf)
          h[mf] = (_Float16)__expf(sacc[nf][mf][r]);
        int byte = nl * 128 + ((((l15 >> 1) ^ (nl & 7))) << 4) + ((l15 & 1) << 3);
        *(half4*)(ebase + byte) = h;
      }

    // ---- GEMM2: oacc[c][n] += W'[c][m-tile] * E^T[m-tile][n] ----
    half8 efrag[2][2];
#pragma unroll
    for (int nf = 0; nf < 2; ++nf)
#pragma unroll
      for (int ks = 0; ks < 2; ++ks) {
        int nl = nf * 16 + l15;
        int slot = (ks * 4 + lhi) ^ (nl & 7);
        efrag[nf][ks] = *(const half8*)(ebase + nl * 128 + (slot << 4));
      }
#pragma unroll
    for (int ks = 0; ks < 2; ++ks)
#pragma unroll
      for (int cf = 0; cf < 4; ++cf)
#pragma unroll
        for (int nf = 0; nf < 2; ++nf)
          oacc[cf][nf] = __builtin_amdgcn_mfma_f32_16x16x32_f16(
              wfrag[cf][ks], efrag[nf][ks], oacc[cf][nf], 0, 0, 0);

    if (mi + 1 < MITER) {
#pragma unroll
      for (int mf = 0; mf < 4; ++mf)
#pragma unroll
        for (int ks = 0; ks < 2; ++ks)
          bfrag[mf][ks] = bnext[mf][ks];
    }
  }

  // ---- store: D rows = c, cols = n -> 64B-coalesced per 16-lane group ----
  float* ob = out + b * CC * HWN;
#pragma unroll
  for (int cf = 0; cf < 4; ++cf)
#pragma unroll
    for (int nf = 0; nf < 2; ++nf)
#pragma unroll
      for (int r = 0; r < 4; ++r) {
        int c = cf * 16 + lhi * 4 + r;
        int n = n0 + wv * 32 + nf * 16 + l15;
        ob[c * HWN + n] = oacc[cf][nf][r] * INV_SCALE;
      }
}

extern "C" void kernel_launch(void* const* d_in, const int* in_sizes, int n_in,
                              void* d_out, int out_size, void* d_ws, size_t ws_size,
                              hipStream_t stream) {
  const float* K = (const float*)d_in[0];
  const float* Q = (const float*)d_in[1];
  const float* V = (const float*)d_in[2];
  float* out = (float*)d_out;
  char* ws = (char*)d_ws;
  // ws layout (all 256B-aligned): kpt f16 | vp f32 | wq f16 | colsum f32
  _Float16* kpt   = (_Float16*)(ws);                          // 294912 B
  float*    vp    = (float*)(ws + 294912);                    // 589824 B
  _Float16* wq    = (_Float16*)(ws + 294912 + 589824);        // 294912 B
  float*    colsum = (float*)(ws + 294912 + 589824 + 294912); // 9216 B

  hipMemsetAsync(colsum, 0, BB * MP * sizeof(float), stream);
  pool_kernel<<<(2 * BB * CC * MP) / 256, 256, 0, stream>>>(K, V, kpt, vp);
  colsum_kernel<<<dim3(HWN / NT, BB), 256, 0, stream>>>(Q, kpt, colsum);
  wprep_kernel<<<(BB * CC * MP) / 256, 256, 0, stream>>>(vp, colsum, wq);
  attn_main_kernel<<<dim3(HWN / NT, BB), 256, 0, stream>>>(Q, kpt, wq, out);
}

// Round 3
// 101.934 us; speedup vs baseline: 1.7694x; 1.5773x over previous
//
#include <hip/hip_runtime.h>

#define BB 4
#define CC 64
#define HH 192
#define WW 192
#define HWN (HH*WW)            // 36864
#define KH 4
#define KW 16
#define PW (WW/KW)             // 12
#define MP ((HH/KH)*(WW/KW))   // 576
#define NT 128                 // n-tile per block
#define MT 64                  // m-tile per iteration
#define MITER (MP/MT)          // 9
#define SCALE_W 65536.0f
#define INV_SCALE (1.0f/65536.0f)

typedef _Float16 half8 __attribute__((ext_vector_type(8)));
typedef _Float16 half4 __attribute__((ext_vector_type(4)));
typedef float floatx4 __attribute__((ext_vector_type(4)));

// kptF fragment order (GEMM1 B-operand, cols permuted m=l15*4+mf):
//   chunk = ((b*9+mi)*4+mf)*2+ks ; f16 idx = chunk*512 + lane*8 + e
//   value = Kp[b][m=mi*64+(lane&15)*4+mf][c=ks*32+(lane>>4)*8+e]
// wqF fragment order (GEMM2 A-operand):
//   chunk = ((b*9+mi)*4+cf)*2+ks ; f16 idx = chunk*512 + lane*8 + e
//   value = W'[b][c=cf*16+(lane&15)][m=mi*64+ks*32+(lane>>4)*8+e]

// ---------------- pooling: kptF (f16 frag-order) and Vp (f32, [b][c][m]) ---
__global__ __launch_bounds__(256) void pool_kernel(
    const float* __restrict__ Kin, const float* __restrict__ Vin,
    _Float16* __restrict__ kptF, float* __restrict__ vp) {
  int t = blockIdx.x * 256 + threadIdx.x;
  const int total = BB * CC * MP;
  bool isV = t >= total;
  int idx = isV ? t - total : t;
  int m = idx % MP;
  int c = (idx / MP) % CC;
  int b = idx / (MP * CC);
  int mh = m / PW, mw = m % PW;
  const float* src = (isV ? Vin : Kin) + (((b * CC + c) * HH + mh * KH) * WW + mw * KW);
  float s = 0.f;
#pragma unroll
  for (int r = 0; r < KH; ++r) {
    const float4* row = (const float4*)(src + r * WW);
#pragma unroll
    for (int j = 0; j < KW / 4; ++j) {
      float4 v = row[j];
      s += v.x + v.y + v.z + v.w;
    }
  }
  s *= (1.0f / (KH * KW));
  if (isV) {
    vp[(b * CC + c) * MP + m] = s;
  } else {
    int mi = m >> 6, mloc = m & 63, l15 = mloc >> 2, mf = mloc & 3;
    int ks = c >> 5, lhi = (c >> 3) & 3, e = c & 7;
    int lane = lhi * 16 + l15;
    kptF[(((((b * MITER + mi) * 4 + mf) * 2 + ks)) * 64 + lane) * 8 + e] = (_Float16)s;
  }
}

// ---------------- pass A: colsum[b][m] = sum_n exp(scores[b][n][m]) --------
// 2-deep pipeline: GEMM1(mi) overlaps exp/reduce(mi-1).
__global__ __launch_bounds__(256) void colsum_kernel(
    const float* __restrict__ Q, const _Float16* __restrict__ kptF,
    float* __restrict__ colsum) {
  __shared__ float cs[MP];
  int b = blockIdx.y;
  int n0 = blockIdx.x * NT;
  int tid = threadIdx.x;
  int wv = tid >> 6;
  int lane = tid & 63;
  int l15 = lane & 15, lhi = lane >> 4;

  for (int i = tid; i < MP; i += 256) cs[i] = 0.f;
  __syncthreads();

  const float* Qb = Q + b * CC * HWN;
  int nrow = n0 + wv * 32 + l15;
  half8 afrag[2][2];
#pragma unroll
  for (int nf = 0; nf < 2; ++nf)
#pragma unroll
    for (int ks = 0; ks < 2; ++ks) {
      int cbase = ks * 32 + lhi * 8;
      int n = nrow + nf * 16;
#pragma unroll
      for (int e = 0; e < 8; ++e)
        afrag[nf][ks][e] = (_Float16)Qb[(cbase + e) * HWN + n];
    }

  const _Float16* kb = kptF + b * MITER * 8 * 512;
  floatx4 zero = {0.f, 0.f, 0.f, 0.f};

  half8 bb[2][4][2];        // double-banked B fragments
  floatx4 sacc[2][2][4];    // double-banked score acc [parity][nf][mf]

#pragma unroll
  for (int mf = 0; mf < 4; ++mf)
#pragma unroll
    for (int ks = 0; ks < 2; ++ks)
      bb[0][mf][ks] = *(const half8*)(kb + ((0 * 4 + mf) * 2 + ks) * 512 + lane * 8);
#pragma unroll
  for (int mf = 0; mf < 4; ++mf)
#pragma unroll
    for (int ks = 0; ks < 2; ++ks)
      bb[1][mf][ks] = *(const half8*)(kb + ((1 * 4 + mf) * 2 + ks) * 512 + lane * 8);

  // body 0: GEMM1(0) only
#pragma unroll
  for (int nf = 0; nf < 2; ++nf)
#pragma unroll
    for (int mf = 0; mf < 4; ++mf) sacc[0][nf][mf] = zero;
  __builtin_amdgcn_s_setprio(1);
#pragma unroll
  for (int ks = 0; ks < 2; ++ks)
#pragma unroll
    for (int nf = 0; nf < 2; ++nf)
#pragma unroll
      for (int mf = 0; mf < 4; ++mf)
        sacc[0][nf][mf] = __builtin_amdgcn_mfma_f32_16x16x32_f16(
            afrag[nf][ks], bb[0][mf][ks], sacc[0][nf][mf], 0, 0, 0);
  __builtin_amdgcn_s_setprio(0);

#pragma unroll
  for (int mi = 1; mi <= 8; ++mi) {
    int cur = mi & 1, prv = (mi - 1) & 1;
    if (mi + 1 <= 8) {
#pragma unroll
      for (int mf = 0; mf < 4; ++mf)
#pragma unroll
        for (int ks = 0; ks < 2; ++ks)
          bb[(mi + 1) & 1][mf][ks] =
              *(const half8*)(kb + (((mi + 1) * 4 + mf) * 2 + ks) * 512 + lane * 8);
    }
#pragma unroll
    for (int nf = 0; nf < 2; ++nf)
#pragma unroll
      for (int mf = 0; mf < 4; ++mf) sacc[cur][nf][mf] = zero;
    __builtin_amdgcn_s_setprio(1);
#pragma unroll
    for (int ks = 0; ks < 2; ++ks)
#pragma unroll
      for (int nf = 0; nf < 2; ++nf)
#pragma unroll
        for (int mf = 0; mf < 4; ++mf)
          sacc[cur][nf][mf] = __builtin_amdgcn_mfma_f32_16x16x32_f16(
              afrag[nf][ks], bb[cur][mf][ks], sacc[cur][nf][mf], 0, 0, 0);
    __builtin_amdgcn_s_setprio(0);
    // reduce(mi-1): permuted col l15 -> m = (mi-1)*64 + l15*4 + mf
#pragma unroll
    for (int mf = 0; mf < 4; ++mf) {
      float s = 0.f;
#pragma unroll
      for (int nf = 0; nf < 2; ++nf)
#pragma unroll
        for (int r = 0; r < 4; ++r)
          s += __expf(sacc[prv][nf][mf][r]);
      s += __shfl_xor(s, 16);
      s += __shfl_xor(s, 32);
      if (lane < 16) atomicAdd(&cs[(mi - 1) * MT + l15 * 4 + mf], s);
    }
  }
  // reduce(8)
#pragma unroll
  for (int mf = 0; mf < 4; ++mf) {
    float s = 0.f;
#pragma unroll
    for (int nf = 0; nf < 2; ++nf)
#pragma unroll
      for (int r = 0; r < 4; ++r)
        s += __expf(sacc[0][nf][mf][r]);
    s += __shfl_xor(s, 16);
    s += __shfl_xor(s, 32);
    if (lane < 16) atomicAdd(&cs[8 * MT + l15 * 4 + mf], s);
  }
  __syncthreads();
  for (int i = tid; i < MP; i += 256) atomicAdd(&colsum[b * MP + i], cs[i]);
}

// ---------------- W' = Vp/colsum * 2^16 (f16, frag-order) ------------------
__global__ __launch_bounds__(256) void wprep_kernel(
    const float* __restrict__ vp, const float* __restrict__ colsum,
    _Float16* __restrict__ wqF) {
  int t = blockIdx.x * 256 + threadIdx.x;
  int m = t % MP;
  int c = (t / MP) % CC;
  int b = t / (CC * MP);
  float w = vp[t] / colsum[b * MP + m] * SCALE_W;
  int cf = c >> 4, l15 = c & 15;
  int mi = m >> 6, mloc = m & 63;
  int ks = mloc >> 5, lhi = (mloc >> 3) & 3, e = mloc & 7;
  int lane = lhi * 16 + l15;
  wqF[((((b * MITER + mi) * 4 + cf) * 2 + ks) * 64 + lane) * 8 + e] = (_Float16)w;
}

// ---------------- pass B: out[b][c][n] = sum_m W'[c][m]*E[n][m] * 2^-16 ----
// 2-deep pipeline: body(mi) = GEMM1(mi) || GEMM2(mi-1); E double-buffered.
__global__ __launch_bounds__(256) void attn_main_kernel(
    const float* __restrict__ Q, const _Float16* __restrict__ kptF,
    const _Float16* __restrict__ wqF, float* __restrict__ out) {
  __shared__ char elds[4 * 8192];  // 4 waves x 2 bufs x 4KB
  int b = blockIdx.y;
  int n0 = blockIdx.x * NT;
  int tid = threadIdx.x;
  int wv = tid >> 6;
  int lane = tid & 63;
  int l15 = lane & 15, lhi = lane >> 4;
  char* eb0 = elds + wv * 8192;
  char* eb1 = eb0 + 4096;

  const float* Qb = Q + b * CC * HWN;
  int nrow = n0 + wv * 32 + l15;
  half8 afrag[2][2];
#pragma unroll
  for (int nf = 0; nf < 2; ++nf)
#pragma unroll
    for (int ks = 0; ks < 2; ++ks) {
      int cbase = ks * 32 + lhi * 8;
      int n = nrow + nf * 16;
#pragma unroll
      for (int e = 0; e < 8; ++e)
        afrag[nf][ks][e] = (_Float16)Qb[(cbase + e) * HWN + n];
    }

  floatx4 zero = {0.f, 0.f, 0.f, 0.f};
  floatx4 oacc[4][2];
#pragma unroll
  for (int cf = 0; cf < 4; ++cf)
#pragma unroll
    for (int nf = 0; nf < 2; ++nf) oacc[cf][nf] = zero;

  const _Float16* kb = kptF + b * MITER * 8 * 512;
  const _Float16* wb = wqF + b * MITER * 8 * 512;

  half8 bb[2][4][2];  // B fragments (kptF), double-banked
  half8 ww[2][4][2];  // W fragments (wqF), double-banked
  floatx4 sacc[2][4];

  // prologue loads: bfrag(0), wfrag(0)
#pragma unroll
  for (int mf = 0; mf < 4; ++mf)
#pragma unroll
    for (int ks = 0; ks < 2; ++ks)
      bb[0][mf][ks] = *(const half8*)(kb + ((0 * 4 + mf) * 2 + ks) * 512 + lane * 8);
#pragma unroll
  for (int cf = 0; cf < 4; ++cf)
#pragma unroll
    for (int ks = 0; ks < 2; ++ks)
      ww[0][cf][ks] = *(const half8*)(wb + ((0 * 4 + cf) * 2 + ks) * 512 + lane * 8);

  // body 0: GEMM1(0) + exp-write(0) ; prefetch bfrag(1)
#pragma unroll
  for (int mf = 0; mf < 4; ++mf)
#pragma unroll
    for (int ks = 0; ks < 2; ++ks)
      bb[1][mf][ks] = *(const half8*)(kb + ((1 * 4 + mf) * 2 + ks) * 512 + lane * 8);
#pragma unroll
  for (int nf = 0; nf < 2; ++nf)
#pragma unroll
    for (int mf = 0; mf < 4; ++mf) sacc[nf][mf] = zero;
  __builtin_amdgcn_s_setprio(1);
#pragma unroll
  for (int ks = 0; ks < 2; ++ks)
#pragma unroll
    for (int nf = 0; nf < 2; ++nf)
#pragma unroll
      for (int mf = 0; mf < 4; ++mf)
        sacc[nf][mf] = __builtin_amdgcn_mfma_f32_16x16x32_f16(
            afrag[nf][ks], bb[0][mf][ks], sacc[nf][mf], 0, 0, 0);
  __builtin_amdgcn_s_setprio(0);
#pragma unroll
  for (int nf = 0; nf < 2; ++nf)
#pragma unroll
    for (int r = 0; r < 4; ++r) {
      int nl = nf * 16 + lhi * 4 + r;
      half4 h;
#pragma unroll
      for (int mf = 0; mf < 4; ++mf) h[mf] = (_Float16)__expf(sacc[nf][mf][r]);
      int byte = nl * 128 + ((((l15 >> 1) ^ (nl & 7))) << 4) + ((l15 & 1) << 3);
      *(half4*)(eb0 + byte) = h;
    }

  // steady bodies: mi = 1..8
#pragma unroll
  for (int mi = 1; mi <= 8; ++mi) {
    int cur = mi & 1, prv = (mi - 1) & 1;
    char* ebR = prv ? eb1 : eb0;   // read E(mi-1)
    char* ebW = cur ? eb1 : eb0;   // write E(mi)

    // E(mi-1) fragments from LDS (latency hidden under GEMM1)
    half8 ef[2][2];
#pragma unroll
    for (int nf = 0; nf < 2; ++nf)
#pragma unroll
      for (int ks = 0; ks < 2; ++ks) {
        int nl = nf * 16 + l15;
        int slot = (ks * 4 + lhi) ^ (nl & 7);
        ef[nf][ks] = *(const half8*)(ebR + nl * 128 + (slot << 4));
      }

    // prefetch bfrag(mi+1)
    if (mi + 1 <= 8) {
#pragma unroll
      for (int mf = 0; mf < 4; ++mf)
#pragma unroll
        for (int ks = 0; ks < 2; ++ks)
          bb[(mi + 1) & 1][mf][ks] =
              *(const half8*)(kb + (((mi + 1) * 4 + mf) * 2 + ks) * 512 + lane * 8);
    }

    // GEMM1(mi)
#pragma unroll
    for (int nf = 0; nf < 2; ++nf)
#pragma unroll
      for (int mf = 0; mf < 4; ++mf) sacc[nf][mf] = zero;
    __builtin_amdgcn_s_setprio(1);
#pragma unroll
    for (int ks = 0; ks < 2; ++ks)
#pragma unroll
      for (int nf = 0; nf < 2; ++nf)
#pragma unroll
        for (int mf = 0; mf < 4; ++mf)
          sacc[nf][mf] = __builtin_amdgcn_mfma_f32_16x16x32_f16(
              afrag[nf][ks], bb[cur][mf][ks], sacc[nf][mf], 0, 0, 0);

    // GEMM2(mi-1)
#pragma unroll
    for (int ks = 0; ks < 2; ++ks)
#pragma unroll
      for (int cf = 0; cf < 4; ++cf)
#pragma unroll
        for (int nf = 0; nf < 2; ++nf)
          oacc[cf][nf] = __builtin_amdgcn_mfma_f32_16x16x32_f16(
              ww[prv][cf][ks], ef[nf][ks], oacc[cf][nf], 0, 0, 0);
    __builtin_amdgcn_s_setprio(0);

    // load wfrag(mi) into bank cur (its old tile mi-2 is dead)
#pragma unroll
    for (int cf = 0; cf < 4; ++cf)
#pragma unroll
      for (int ks = 0; ks < 2; ++ks)
        ww[cur][cf][ks] = *(const half8*)(wb + ((mi * 4 + cf) * 2 + ks) * 512 + lane * 8);

    // exp-write(mi)
#pragma unroll
    for (int nf = 0; nf < 2; ++nf)
#pragma unroll
      for (int r = 0; r < 4; ++r) {
        int nl = nf * 16 + lhi * 4 + r;
        half4 h;
#pragma unroll
        for (int mf = 0; mf < 4; ++mf) h[mf] = (_Float16)__expf(sacc[nf][mf][r]);
        int byte = nl * 128 + ((((l15 >> 1) ^ (nl & 7))) << 4) + ((l15 & 1) << 3);
        *(half4*)(ebW + byte) = h;
      }
  }

  // epilogue: GEMM2(8) from buf0 (8&1==0), wfrag bank 0
  {
    half8 ef[2][2];
#pragma unroll
    for (int nf = 0; nf < 2; ++nf)
#pragma unroll
      for (int ks = 0; ks < 2; ++ks) {
        int nl = nf * 16 + l15;
        int slot = (ks * 4 + lhi) ^ (nl & 7);
        ef[nf][ks] = *(const half8*)(eb0 + nl * 128 + (slot << 4));
      }
    __builtin_amdgcn_s_setprio(1);
#pragma unroll
    for (int ks = 0; ks < 2; ++ks)
#pragma unroll
      for (int cf = 0; cf < 4; ++cf)
#pragma unroll
        for (int nf = 0; nf < 2; ++nf)
          oacc[cf][nf] = __builtin_amdgcn_mfma_f32_16x16x32_f16(
              ww[0][cf][ks], ef[nf][ks], oacc[cf][nf], 0, 0, 0);
    __builtin_amdgcn_s_setprio(0);
  }

  float* ob = out + b * CC * HWN;
#pragma unroll
  for (int cf = 0; cf < 4; ++cf)
#pragma unroll
    for (int nf = 0; nf < 2; ++nf)
#pragma unroll
      for (int r = 0; r < 4; ++r) {
        int c = cf * 16 + lhi * 4 + r;
        int n = n0 + wv * 32 + nf * 16 + l15;
        ob[c * HWN + n] = oacc[cf][nf][r] * INV_SCALE;
      }
}

extern "C" void kernel_launch(void* const* d_in, const int* in_sizes, int n_in,
                              void* d_out, int out_size, void* d_ws, size_t ws_size,
                              hipStream_t stream) {
  const float* K = (const float*)d_in[0];
  const float* Q = (const float*)d_in[1];
  const float* V = (const float*)d_in[2];
  float* out = (float*)d_out;
  char* ws = (char*)d_ws;
  _Float16* kptF  = (_Float16*)(ws);                          // 294912 B
  float*    vp    = (float*)(ws + 294912);                    // 589824 B
  _Float16* wqF   = (_Float16*)(ws + 294912 + 589824);        // 294912 B
  float*    colsum = (float*)(ws + 294912 + 589824 + 294912); // 9216 B

  hipMemsetAsync(colsum, 0, BB * MP * sizeof(float), stream);
  pool_kernel<<<(2 * BB * CC * MP) / 256, 256, 0, stream>>>(K, V, kptF, vp);
  colsum_kernel<<<dim3(HWN / NT, BB), 256, 0, stream>>>(Q, kptF, colsum);
  wprep_kernel<<<(BB * CC * MP) / 256, 256, 0, stream>>>(vp, colsum, wqF);
  attn_main_kernel<<<dim3(HWN / NT, BB), 256, 0, stream>>>(Q, kptF, wqF, out);
}